// Round 9
// baseline (82.587 us; speedup 1.0000x reference)
//
#include <hip/hip_runtime.h>

// Problem constants (fixed by setup_inputs)
#define N_BATCH 32
#define C_IN    64
#define H_IN    32
#define W_IN    32
#define C_OUT   512
#define H_OUT   32
#define W_OUT   32

// Native clang vector type — required by __builtin_nontemporal_store
// (HIP's float4 is a struct and is rejected).
typedef float f32x4 __attribute__((ext_vector_type(4)));

// OP_COEFFS folded to compile-time immediates (no __constant__ segment, no
// module-scope device state).
__device__ __forceinline__ void op_coeffs(int i, float& c0, float& c1, float& c2, float& c3) {
    constexpr float T[16][4] = {
        {0.f,0.f,0.f,0.f}, {0.f,0.f,0.f,1.f}, {0.f,1.f,0.f,-1.f}, {0.f,1.f,0.f,0.f},
        {0.f,0.f,1.f,-1.f}, {0.f,0.f,1.f,0.f}, {0.f,1.f,1.f,-2.f}, {0.f,1.f,1.f,-1.f},
        {1.f,-1.f,-1.f,1.f}, {1.f,-1.f,-1.f,2.f}, {1.f,0.f,-1.f,0.f}, {1.f,0.f,-1.f,1.f},
        {1.f,-1.f,0.f,0.f}, {1.f,-1.f,0.f,1.f}, {1.f,0.f,0.f,-1.f}, {1.f,0.f,0.f,0.f}
    };
    c0 = T[i][0]; c1 = T[i][1]; c2 = T[i][2]; c3 = T[i][3];
}

__device__ __forceinline__ float gather_x(const float* __restrict__ x,
                                          int nbase, int s, int oh, int ow) {
    int ch = (s >> 16) & 0xffff;
    int ry = (s >> 8) & 0xff;
    int rx = s & 0xff;
    int r = oh + ry - 1;          // PAD_H = 1
    int c = ow + rx - 1;          // PAD_W = 1
    bool ok = ((unsigned)r < (unsigned)H_IN) && ((unsigned)c < (unsigned)W_IN);
    return ok ? x[nbase + ch * (H_IN * W_IN) + r * W_IN + c] : 0.0f;
}

// 1024 threads/block, ONE output position per thread:
// minimal per-thread live state (8 gather values + 4 outputs) -> VGPR <= 64
// -> 8 waves/SIMD occupancy; gather latency hidden by TLP, keeping the HBM
// write port continuously fed.
__global__ __launch_bounds__(1024)
void conv_logic_kernel(const float* __restrict__ x,
                       const float* __restrict__ weights,
                       const int*   __restrict__ sel,
                       float* __restrict__ y) {
    const int c = blockIdx.x;   // C_OUT
    const int n = blockIdx.y;   // N

    __shared__ float4 s_coef[4];   // per p: (k0, ka, kb, kab)
    __shared__ int    s_sel[8];

    if (threadIdx.x < 8) s_sel[threadIdx.x] = sel[c * 8 + threadIdx.x];
    if (threadIdx.x < 4) {
        const int p = threadIdx.x;
        const float* w = weights + (c * 4 + p) * 16;
        float v[16];
        float m = -3.402823466e+38f;
        #pragma unroll
        for (int i = 0; i < 16; ++i) { v[i] = w[i]; m = fmaxf(m, v[i]); }
        float ssum = 0.f;
        #pragma unroll
        for (int i = 0; i < 16; ++i) { v[i] = __expf(v[i] - m); ssum += v[i]; }
        const float inv = 1.0f / ssum;
        float c0 = 0.f, c1 = 0.f, c2 = 0.f, c3 = 0.f;
        #pragma unroll
        for (int i = 0; i < 16; ++i) {
            float t0, t1, t2, t3;
            op_coeffs(i, t0, t1, t2, t3);   // compile-time immediates after unroll
            c0 = fmaf(v[i], t0, c0);
            c1 = fmaf(v[i], t1, c1);
            c2 = fmaf(v[i], t2, c2);
            c3 = fmaf(v[i], t3, c3);
        }
        s_coef[p] = make_float4(c0 * inv, c1 * inv, c2 * inv, c3 * inv);
    }
    __syncthreads();

    const int nbase = n * (C_IN * H_IN * W_IN);
    f32x4* __restrict__ yv = reinterpret_cast<f32x4*>(y) +
                             (size_t)(n * C_OUT + c) * (H_OUT * W_OUT);

    const int pos = threadIdx.x;     // 0..1023
    const int oh = pos >> 5;
    const int ow = pos & 31;

    // Issue all 8 gathers first (independent), then the arithmetic.
    const float a0 = gather_x(x, nbase, s_sel[0], oh, ow);
    const float b0 = gather_x(x, nbase, s_sel[1], oh, ow);
    const float a1 = gather_x(x, nbase, s_sel[2], oh, ow);
    const float b1 = gather_x(x, nbase, s_sel[3], oh, ow);
    const float a2 = gather_x(x, nbase, s_sel[4], oh, ow);
    const float b2 = gather_x(x, nbase, s_sel[5], oh, ow);
    const float a3 = gather_x(x, nbase, s_sel[6], oh, ow);
    const float b3 = gather_x(x, nbase, s_sel[7], oh, ow);

    const float4 cf0 = s_coef[0];
    const float4 cf1 = s_coef[1];
    const float4 cf2 = s_coef[2];
    const float4 cf3 = s_coef[3];

    f32x4 out;
    out.x = fmaf(cf0.w * a0, b0, fmaf(cf0.y, a0, fmaf(cf0.z, b0, cf0.x)));
    out.y = fmaf(cf1.w * a1, b1, fmaf(cf1.y, a1, fmaf(cf1.z, b1, cf1.x)));
    out.z = fmaf(cf2.w * a2, b2, fmaf(cf2.y, a2, fmaf(cf2.z, b2, cf2.x)));
    out.w = fmaf(cf3.w * a3, b3, fmaf(cf3.y, a3, fmaf(cf3.z, b3, cf3.x)));

    // Write-once 268 MB stream: nontemporal so it doesn't churn L2.
    __builtin_nontemporal_store(out, &yv[pos]);
}

extern "C" void kernel_launch(void* const* d_in, const int* in_sizes, int n_in,
                              void* d_out, int out_size, void* d_ws, size_t ws_size,
                              hipStream_t stream) {
    const float* x       = (const float*)d_in[0];
    const float* weights = (const float*)d_in[1];
    const int*   sel     = (const int*)d_in[2];
    float* y             = (float*)d_out;

    dim3 grid(C_OUT, N_BATCH);
    conv_logic_kernel<<<grid, 1024, 0, stream>>>(x, weights, sel, y);
}

// Round 10
// 56.920 us; speedup vs baseline: 1.4509x; 1.4509x over previous
//
#include <hip/hip_runtime.h>

// Problem constants (fixed by setup_inputs)
#define N_BATCH 32
#define C_IN    64
#define H_IN    32
#define W_IN    32
#define C_OUT   512
#define H_OUT   32
#define W_OUT   32

typedef float f32x4 __attribute__((ext_vector_type(4)));

__device__ __forceinline__ void op_coeffs(int i, float& c0, float& c1, float& c2, float& c3) {
    constexpr float T[16][4] = {
        {0.f,0.f,0.f,0.f}, {0.f,0.f,0.f,1.f}, {0.f,1.f,0.f,-1.f}, {0.f,1.f,0.f,0.f},
        {0.f,0.f,1.f,-1.f}, {0.f,0.f,1.f,0.f}, {0.f,1.f,1.f,-2.f}, {0.f,1.f,1.f,-1.f},
        {1.f,-1.f,-1.f,1.f}, {1.f,-1.f,-1.f,2.f}, {1.f,0.f,-1.f,0.f}, {1.f,0.f,-1.f,1.f},
        {1.f,-1.f,0.f,0.f}, {1.f,-1.f,0.f,1.f}, {1.f,0.f,0.f,-1.f}, {1.f,0.f,0.f,0.f}
    };
    c0 = T[i][0]; c1 = T[i][1]; c2 = T[i][2]; c3 = T[i][3];
}

// ---------- kernel 1: coefficient table (512*4 entries -> d_ws, 32 KB) ----------
__global__ __launch_bounds__(256)
void coef_kernel(const float* __restrict__ weights, f32x4* __restrict__ coef) {
    const int idx = blockIdx.x * 256 + threadIdx.x;   // (c*4 + p), 0..2047
    if (idx >= C_OUT * 4) return;
    const float* w = weights + idx * 16;
    float v[16];
    float m = -3.402823466e+38f;
    #pragma unroll
    for (int i = 0; i < 16; ++i) { v[i] = w[i]; m = fmaxf(m, v[i]); }
    float ssum = 0.f;
    #pragma unroll
    for (int i = 0; i < 16; ++i) { v[i] = __expf(v[i] - m); ssum += v[i]; }
    const float inv = 1.0f / ssum;
    float c0 = 0.f, c1 = 0.f, c2 = 0.f, c3 = 0.f;
    #pragma unroll
    for (int i = 0; i < 16; ++i) {
        float t0, t1, t2, t3;
        op_coeffs(i, t0, t1, t2, t3);
        c0 = fmaf(v[i], t0, c0);
        c1 = fmaf(v[i], t1, c1);
        c2 = fmaf(v[i], t2, c2);
        c3 = fmaf(v[i], t3, c3);
    }
    f32x4 out; out.x = c0 * inv; out.y = c1 * inv; out.z = c2 * inv; out.w = c3 * inv;
    coef[idx] = out;
}

__device__ __forceinline__ float gather_x(const float* __restrict__ x,
                                          int nbase, int s, int oh, int ow) {
    int ch = (s >> 16) & 0xffff;
    int ry = (s >> 8) & 0xff;
    int rx = s & 0xff;
    int r = oh + ry - 1;          // PAD_H = 1
    int c = ow + rx - 1;          // PAD_W = 1
    bool ok = ((unsigned)r < (unsigned)H_IN) && ((unsigned)c < (unsigned)W_IN);
    return ok ? x[nbase + ch * (H_IN * W_IN) + r * W_IN + c] : 0.0f;
}

// ---------- kernel 2: main stream — no LDS, no __syncthreads ----------
// coef/sel loads are block-uniform (blockIdx-based address) -> scalar s_load;
// waves begin gather/store immediately, no prologue barrier to expose.
__global__ __launch_bounds__(256)
void conv_main_kernel(const float* __restrict__ x,
                      const f32x4* __restrict__ coef,
                      const int*   __restrict__ sel,
                      float* __restrict__ y) {
    const int c = blockIdx.x;   // C_OUT
    const int n = blockIdx.y;   // N

    // Block-uniform scalar loads (L2-resident: sel 16KB, coef 32KB).
    const int sl0 = sel[c * 8 + 0], sl1 = sel[c * 8 + 1];
    const int sl2 = sel[c * 8 + 2], sl3 = sel[c * 8 + 3];
    const int sl4 = sel[c * 8 + 4], sl5 = sel[c * 8 + 5];
    const int sl6 = sel[c * 8 + 6], sl7 = sel[c * 8 + 7];
    const f32x4 cf0 = coef[c * 4 + 0];
    const f32x4 cf1 = coef[c * 4 + 1];
    const f32x4 cf2 = coef[c * 4 + 2];
    const f32x4 cf3 = coef[c * 4 + 3];

    const int nbase = n * (C_IN * H_IN * W_IN);
    f32x4* __restrict__ yv = reinterpret_cast<f32x4*>(y) +
                             (size_t)(n * C_OUT + c) * (H_OUT * W_OUT);

    #pragma unroll
    for (int k = 0; k < 4; ++k) {
        const int pos = threadIdx.x + k * 256;   // 0..1023
        const int oh = pos >> 5;
        const int ow = pos & 31;

        float a, b;
        f32x4 out;

        a = gather_x(x, nbase, sl0, oh, ow);
        b = gather_x(x, nbase, sl1, oh, ow);
        out.x = fmaf(cf0.w * a, b, fmaf(cf0.y, a, fmaf(cf0.z, b, cf0.x)));

        a = gather_x(x, nbase, sl2, oh, ow);
        b = gather_x(x, nbase, sl3, oh, ow);
        out.y = fmaf(cf1.w * a, b, fmaf(cf1.y, a, fmaf(cf1.z, b, cf1.x)));

        a = gather_x(x, nbase, sl4, oh, ow);
        b = gather_x(x, nbase, sl5, oh, ow);
        out.z = fmaf(cf2.w * a, b, fmaf(cf2.y, a, fmaf(cf2.z, b, cf2.x)));

        a = gather_x(x, nbase, sl6, oh, ow);
        b = gather_x(x, nbase, sl7, oh, ow);
        out.w = fmaf(cf3.w * a, b, fmaf(cf3.y, a, fmaf(cf3.z, b, cf3.x)));

        // Write-once 268 MB stream: nontemporal, don't churn L2.
        __builtin_nontemporal_store(out, &yv[pos]);
    }
}

// ---------- fused fallback (only if d_ws is too small; R8 structure) ----------
__global__ __launch_bounds__(256)
void conv_fused_kernel(const float* __restrict__ x,
                       const float* __restrict__ weights,
                       const int*   __restrict__ sel,
                       float* __restrict__ y) {
    const int c = blockIdx.x;
    const int n = blockIdx.y;

    __shared__ float4 s_coef[4];
    __shared__ int    s_sel[8];

    if (threadIdx.x < 8) s_sel[threadIdx.x] = sel[c * 8 + threadIdx.x];
    if (threadIdx.x < 4) {
        const int p = threadIdx.x;
        const float* w = weights + (c * 4 + p) * 16;
        float v[16];
        float m = -3.402823466e+38f;
        #pragma unroll
        for (int i = 0; i < 16; ++i) { v[i] = w[i]; m = fmaxf(m, v[i]); }
        float ssum = 0.f;
        #pragma unroll
        for (int i = 0; i < 16; ++i) { v[i] = __expf(v[i] - m); ssum += v[i]; }
        const float inv = 1.0f / ssum;
        float c0 = 0.f, c1 = 0.f, c2 = 0.f, c3 = 0.f;
        #pragma unroll
        for (int i = 0; i < 16; ++i) {
            float t0, t1, t2, t3;
            op_coeffs(i, t0, t1, t2, t3);
            c0 = fmaf(v[i], t0, c0);
            c1 = fmaf(v[i], t1, c1);
            c2 = fmaf(v[i], t2, c2);
            c3 = fmaf(v[i], t3, c3);
        }
        s_coef[p] = make_float4(c0 * inv, c1 * inv, c2 * inv, c3 * inv);
    }
    __syncthreads();

    const int nbase = n * (C_IN * H_IN * W_IN);
    f32x4* __restrict__ yv = reinterpret_cast<f32x4*>(y) +
                             (size_t)(n * C_OUT + c) * (H_OUT * W_OUT);

    const float4 cf0 = s_coef[0], cf1 = s_coef[1], cf2 = s_coef[2], cf3 = s_coef[3];
    const int sl0 = s_sel[0], sl1 = s_sel[1], sl2 = s_sel[2], sl3 = s_sel[3];
    const int sl4 = s_sel[4], sl5 = s_sel[5], sl6 = s_sel[6], sl7 = s_sel[7];

    #pragma unroll
    for (int k = 0; k < 4; ++k) {
        const int pos = threadIdx.x + k * 256;
        const int oh = pos >> 5;
        const int ow = pos & 31;
        float a, b;
        f32x4 out;
        a = gather_x(x, nbase, sl0, oh, ow);
        b = gather_x(x, nbase, sl1, oh, ow);
        out.x = fmaf(cf0.w * a, b, fmaf(cf0.y, a, fmaf(cf0.z, b, cf0.x)));
        a = gather_x(x, nbase, sl2, oh, ow);
        b = gather_x(x, nbase, sl3, oh, ow);
        out.y = fmaf(cf1.w * a, b, fmaf(cf1.y, a, fmaf(cf1.z, b, cf1.x)));
        a = gather_x(x, nbase, sl4, oh, ow);
        b = gather_x(x, nbase, sl5, oh, ow);
        out.z = fmaf(cf2.w * a, b, fmaf(cf2.y, a, fmaf(cf2.z, b, cf2.x)));
        a = gather_x(x, nbase, sl6, oh, ow);
        b = gather_x(x, nbase, sl7, oh, ow);
        out.w = fmaf(cf3.w * a, b, fmaf(cf3.y, a, fmaf(cf3.z, b, cf3.x)));
        __builtin_nontemporal_store(out, &yv[pos]);
    }
}

extern "C" void kernel_launch(void* const* d_in, const int* in_sizes, int n_in,
                              void* d_out, int out_size, void* d_ws, size_t ws_size,
                              hipStream_t stream) {
    const float* x       = (const float*)d_in[0];
    const float* weights = (const float*)d_in[1];
    const int*   sel     = (const int*)d_in[2];
    float* y             = (float*)d_out;

    const size_t coef_bytes = (size_t)C_OUT * 4 * sizeof(f32x4);   // 32 KB
    dim3 grid(C_OUT, N_BATCH);

    if (ws_size >= coef_bytes) {
        f32x4* coef = (f32x4*)d_ws;
        coef_kernel<<<dim3((C_OUT * 4 + 255) / 256), 256, 0, stream>>>(weights, coef);
        conv_main_kernel<<<grid, 256, 0, stream>>>(x, coef, sel, y);
    } else {
        conv_fused_kernel<<<grid, 256, 0, stream>>>(x, weights, sel, y);
    }
}